// Round 15
// baseline (16.527 us; speedup 1.0000x reference)
//
#include <hip/hip_runtime.h>
#include <math.h>
#include <stdint.h>

// FluxGNN1DLatent — round 15: r14 + apply-side latency cuts:
//  * um1 via __shfl_up(u1,1) (lane l-1's u1 IS u[i0-1]; clamp-consistent at
//    row tail) -> 2 u-loads per lane instead of 3.
//  * 1 span per wave (AGRID 512->1034; 16544 waves = total spans) -> halves
//    the per-wave serial latency chain.
// Build (65x63 table via r7 MFMA engine) byte-identical to r14.
// phi[i] = F(a_i, d_i), a = u_l+u_r in [0,2), d = |u_r-u_l| in [0,1);
// T = 0.5*phi tabulated; out = u*selt - (T(n+1)-T(n)).
// Fallback: full round-7 kernel if ws_size < table.

#define LD    32
#define HID   64
#define NN    65536
#define BB    32
#define SPANS 1041                 // fallback kernel: ceil(65536/63)
#define TOTAL_SPANS (BB * SPANS)   // 33312

// ---- table geometry ----
#define NA    65                   // a = ia/32,  ia in [0,64]
#define ND    63                   // d = id/62,  id in [0,62]
#define NPTS  (NA * ND)            // 4095
#define TBL_BYTES ((NPTS + 1) * 4) // +1 slot for selt = 16384 B
#define WPB   4
#define BGRID 32                   // 32 blocks x 4 waves x 32 pts = 4096 slots

typedef __attribute__((ext_vector_type(8))) short bf16x8;
typedef __attribute__((ext_vector_type(4))) float f32x4;
typedef __attribute__((ext_vector_type(2))) float v2f;
typedef __attribute__((ext_vector_type(4))) unsigned int u32x4;

__device__ __forceinline__ uint32_t cvt_pk_bf16(float lo, float hi) {
    uint32_t r;
    asm("v_cvt_pk_bf16_f32 %0, %1, %2" : "=v"(r) : "v"(lo), "v"(hi));
    return r;
}
// gelu(x) = x*(1 - 1/(exp2(C1*x + C3*x^3)+1)); C1=2*log2e*0.79788456
__device__ __forceinline__ v2f gelu2(v2f x) {
    const v2f xx    = x * x;
    const v2f inner = xx * 0.10294322f + 2.3022077f;
    const v2f arg   = x * inner;
    v2f t;
    t.x = __builtin_amdgcn_exp2f(arg.x);
    t.y = __builtin_amdgcn_exp2f(arg.y);
    const v2f dd = t + 1.0f;
    v2f r;
    r.x = __builtin_amdgcn_rcpf(dd.x);
    r.y = __builtin_amdgcn_rcpf(dd.y);
    return x - x * r;
}
// tanh(y) = 1 - 2/(exp2(2*log2e*y)+1)
__device__ __forceinline__ v2f tanh2(v2f y) {
    const v2f a = y * 2.8853901f;
    v2f t;
    t.x = __builtin_amdgcn_exp2f(a.x);
    t.y = __builtin_amdgcn_exp2f(a.y);
    const v2f dd = t + 1.0f;
    v2f r;
    r.x = __builtin_amdgcn_rcpf(dd.x);
    r.y = __builtin_amdgcn_rcpf(dd.y);
    return 1.0f - 2.0f * r;
}

// ============  kernel 1: build table (r7 engine, 32 pts/wave)  ============
__global__ __launch_bounds__(256, 2)
void build_table_mfma4(const float* __restrict__ enc,
                       const float* __restrict__ W1, const float* __restrict__ b1,
                       const float* __restrict__ W2, const float* __restrict__ b2,
                       const float* __restrict__ W3, const float* __restrict__ b3,
                       float* __restrict__ tg)
{
    __shared__ __align__(16) short xT[WPB][2][16][64];
    __shared__ __align__(16) float sv1[HID];
    __shared__ __align__(16) float sv2[HID];

    const int tid = threadIdx.x;
    const int w   = tid >> 6;
    const int l   = tid & 63;
    const int c   = l & 15;
    const int g   = l >> 4;

    if (tid < HID) {
        float a1 = 0.f, a2 = 0.f;
        #pragma unroll
        for (int m = 0; m < LD; ++m) {
            const float e = enc[m];
            a1 = fmaf(e,        W1[m * HID + tid],        a1);
            a2 = fmaf(fabsf(e), W1[(LD + m) * HID + tid], a2);
        }
        sv1[tid] = a1;
        sv2[tid] = a2;
    }

    float S = 0.f;
    #pragma unroll
    for (int m = 0; m < LD; ++m) { const float e = enc[m]; S = fmaf(e, e, S); }
    const float inv = 1.0f / (S + 1e-12f);

    bf16x8 a2f[4][2];
    #pragma unroll
    for (int mt = 0; mt < 4; ++mt)
        #pragma unroll
        for (int kt = 0; kt < 2; ++kt) {
            u32x4 uu;
            #pragma unroll
            for (int p = 0; p < 4; ++p) {
                const int k0 = 32*kt + 8*g + 2*p;
                uu[p] = cvt_pk_bf16(W2[k0 * HID + 16*mt + c],
                                    W2[(k0 + 1) * HID + 16*mt + c]);
            }
            a2f[mt][kt] = __builtin_bit_cast(bf16x8, uu);
        }
    bf16x8 a3f[2][2];
    #pragma unroll
    for (int mt = 0; mt < 2; ++mt)
        #pragma unroll
        for (int kt = 0; kt < 2; ++kt) {
            u32x4 uu;
            #pragma unroll
            for (int p = 0; p < 4; ++p) {
                const int k0 = 32*kt + 8*g + 2*p;
                uu[p] = cvt_pk_bf16(W3[k0 * LD + 16*mt + c],
                                    W3[(k0 + 1) * LD + 16*mt + c]);
            }
            a3f[mt][kt] = __builtin_bit_cast(bf16x8, uu);
        }

    f32x4 b2q[4], b3q[2];
    #pragma unroll
    for (int mt = 0; mt < 4; ++mt)
        b2q[mt] = *reinterpret_cast<const f32x4*>(b2 + 16*mt + 4*g);
    #pragma unroll
    for (int mt = 0; mt < 2; ++mt)
        b3q[mt] = *reinterpret_cast<const f32x4*>(b3 + 16*mt + 4*g);

    // enc pairs scaled by 0.125*inv: tg holds T = 0.5*phi
    const v2f* encv = (const v2f*)enc;
    v2f encp[2][2];
    #pragma unroll
    for (int mt = 0; mt < 2; ++mt) {
        encp[mt][0] = encv[8*mt + 2*g + 0] * (0.125f * inv);
        encp[mt][1] = encv[8*mt + 2*g + 1] * (0.125f * inv);
    }

    __syncthreads();

    const v2f* sv1v = (const v2f*)sv1;
    const v2f* sv2v = (const v2f*)sv2;
    const v2f* b1v  = (const v2f*)b1;
    v2f v1p[2][4], v2p[2][4], b1p[2][4];
    #pragma unroll
    for (int kt = 0; kt < 2; ++kt)
        #pragma unroll
        for (int p = 0; p < 4; ++p) {
            const int idx = 16*kt + 4*g + p;
            v1p[kt][p] = sv1v[idx];
            v2p[kt][p] = sv2v[idx];
            b1p[kt][p] = b1v[idx];
        }

    short* const xs0 = &xT[w][0][0][0];
    short* const xs1 = &xT[w][1][0][0];
    const int swz    = (c & 7) << 1;
    const int rowoff = c * 64;

    auto stageA = [&](float a_, float d_, short* xsl) {
        const v2f av = { a_, a_ };
        const v2f dv = { d_, d_ };
        f32x4 acc[4];
        #pragma unroll
        for (int kt = 0; kt < 2; ++kt) {
            u32x4 uu;
            #pragma unroll
            for (int p = 0; p < 4; ++p) {
                const v2f pre = av * v1p[kt][p] + (dv * v2p[kt][p] + b1p[kt][p]);
                const v2f gg  = gelu2(pre);
                uu[p] = cvt_pk_bf16(gg.x, gg.y);
            }
            const bf16x8 bfrag = __builtin_bit_cast(bf16x8, uu);
            #pragma unroll
            for (int mt = 0; mt < 4; ++mt)
                acc[mt] = __builtin_amdgcn_mfma_f32_16x16x32_bf16(
                              a2f[mt][kt], bfrag, kt == 0 ? b2q[mt] : acc[mt],
                              0, 0, 0);
        }
        #pragma unroll
        for (int mt = 0; mt < 4; ++mt) {
            const v2f y01 = gelu2((v2f){acc[mt][0], acc[mt][1]});
            const v2f y23 = gelu2((v2f){acc[mt][2], acc[mt][3]});
            uint2 pk;
            pk.x = cvt_pk_bf16(y01.x, y01.y);
            pk.y = cvt_pk_bf16(y23.x, y23.y);
            const int cs = (4*mt + g) ^ swz;
            *reinterpret_cast<uint2*>(xsl + rowoff + cs*4) = pk;
        }
    };
    auto stageB = [&](const short* xsl) -> float {
        f32x4 a3acc[2];
        #pragma unroll
        for (int kt = 0; kt < 2; ++kt) {
            const int p = (8*kt + 2*g) ^ swz;
            const bf16x8 bfr =
                *reinterpret_cast<const bf16x8*>(xsl + rowoff + p*4);
            #pragma unroll
            for (int mt = 0; mt < 2; ++mt)
                a3acc[mt] = __builtin_amdgcn_mfma_f32_16x16x32_bf16(
                                a3f[mt][kt], bfr, kt == 0 ? b3q[mt] : a3acc[mt],
                                0, 0, 0);
        }
        v2f sacc = {0.f, 0.f};
        #pragma unroll
        for (int mt = 0; mt < 2; ++mt) {
            sacc += tanh2((v2f){a3acc[mt][0], a3acc[mt][1]}) * encp[mt][0];
            sacc += tanh2((v2f){a3acc[mt][2], a3acc[mt][3]}) * encp[mt][1];
        }
        float s_ = sacc.x + sacc.y;
        s_ += __shfl_xor(s_, 16);
        s_ += __shfl_xor(s_, 32);
        return s_;
    };

    // ---- this wave's 32 table points (clamped to the table domain)
    const int wbase = (blockIdx.x * WPB + w) * 32;
    float af[2], df[2];
    #pragma unroll
    for (int nt = 0; nt < 2; ++nt) {
        int pp = wbase + 16*nt + c;
        pp = pp < NPTS ? pp : NPTS - 1;        // clamp OOB tail lanes
        const int ia  = pp / ND;
        const int idd = pp - ia * ND;
        af[nt] = (float)ia  * (1.0f / 32.0f);
        df[nt] = (float)idd * (1.0f / 62.0f);
    }

    // pipelined: B0 reads xs0 a full stage after A0's store (r7 discipline)
    float phi0, phi1;
    stageA(af[0], df[0], xs0);
    stageA(af[1], df[1], xs1);
    phi0 = stageB(xs0);
    phi1 = stageB(xs1);

    const float myphi = (g & 1) ? phi1 : phi0;   // l<32: g in {0,1}
    const int pid = wbase + l;
    if (l < 32 && pid < NPTS) tg[pid] = myphi;
    if (blockIdx.x == 0 && tid == 0) tg[NPTS] = S * inv;   // selt slot
}

// =====================  kernel 2: apply table (2 interfaces/lane)  ==========
#define APB   1024
#define AGRID 1034                    // 1034*16 = 16544 waves = total spans
#define AWAVES (AGRID * (APB / 64))   // 16544
#define SPANS_A 517                   // ceil(65536/127)
#define TOTAL_SPANS_A (BB * SPANS_A)  // 16544

__global__ __launch_bounds__(APB)
void apply_table(const float* __restrict__ u,
                 const float* __restrict__ tg,
                 float* __restrict__ out)
{
    __shared__ __align__(16) float T[NPTS];       // 16380 B

    const int tid = threadIdx.x;
    {   // vectorized preload: 1023 float4 + 3-element tail (4095 = 1023*4+3)
        const float4* tg4 = reinterpret_cast<const float4*>(tg);
        float4* T4 = reinterpret_cast<float4*>(T);
        for (int k4 = tid; k4 < NPTS / 4; k4 += APB) T4[k4] = tg4[k4];
        if (tid < (NPTS & 3)) T[(NPTS & ~3) + tid] = tg[(NPTS & ~3) + tid];
    }
    const float selt = tg[NPTS];
    __syncthreads();

    const int w = tid >> 6;
    const int l = tid & 63;

    auto lookup = [&](float a, float d) -> float {
        const float ta = a * 32.0f;
        const int   ia = (int)ta;
        const float fa = ta - (float)ia;
        const float td = d * 62.0f;
        const int   idn = (int)td;
        const float fd = td - (float)idn;
        const int base = ia * ND + idn;
        const float g00 = T[base];
        const float g01 = T[base + 1];
        const float g10 = T[base + ND];
        const float g11 = T[base + ND + 1];
        const float gA = fmaf(fd, g01 - g00, g00);
        const float gB = fmaf(fd, g11 - g10, g10);
        return fmaf(fa, gB - gA, gA);             // T = 0.5*phi
    };

    for (int sid = blockIdx.x * (APB / 64) + w; sid < TOTAL_SPANS_A; sid += AWAVES) {
        const int row  = sid / SPANS_A;
        const int span = sid - row * SPANS_A;
        const int n0   = span * 127;
        const float* __restrict__ urow = u + row * NN;

        const int i0 = n0 + 2 * l;                 // interfaces i0, i0+1
        const int im = i0     > NN - 1 ? NN - 1 : i0;
        const int ir = i0 + 1 > NN - 1 ? NN - 1 : i0 + 1;
        const float u0 = urow[im];
        const float u1 = urow[ir];

        // um1 = u[clamp(i0-1)]: lane l-1's u1 is exactly u[i0-1] (clamp-
        // consistent at the row tail since both clamp to u[NN-1]); only
        // lane 0 must load its halo.
        float um1 = __shfl_up(u1, 1);
        if (l == 0) {
            int il = i0 - 1; il = il < 0 ? 0 : (il > NN - 1 ? NN - 1 : il);
            um1 = urow[il];
        }

        const float F0 = lookup(um1 + u0, fabsf(u0 - um1));   // T(i0)
        const float F1 = lookup(u0 + u1, fabsf(u1 - u0));     // T(i0+1)
        const float pn2 = __shfl_down(F0, 1);                 // T(i0+2)

        const int n = n0 + 2 * l;
        if (2 * l < 127 && n < NN)
            out[row * NN + n] = fmaf(u0, selt, -(F1 - F0));
        if (2 * l + 1 < 127 && n + 1 < NN)
            out[row * NN + n + 1] = fmaf(u1, selt, -(pn2 - F1));
    }
}

// =====================  fallback: round-7 MFMA kernel  =====================
#define GRID  2048

__global__ __launch_bounds__(256, 2)
void fluxgnn_mfma(const float* __restrict__ u,  const float* __restrict__ enc,
                  const float* __restrict__ W1, const float* __restrict__ b1,
                  const float* __restrict__ W2, const float* __restrict__ b2,
                  const float* __restrict__ W3, const float* __restrict__ b3,
                  float* __restrict__ out)
{
    __shared__ __align__(16) short xT[WPB][2][16][64];
    __shared__ __align__(16) float sv1[HID];
    __shared__ __align__(16) float sv2[HID];

    const int tid = threadIdx.x;
    const int w   = tid >> 6;
    const int l   = tid & 63;
    const int c   = l & 15;
    const int g   = l >> 4;

    if (tid < HID) {
        float a1 = 0.f, a2 = 0.f;
        #pragma unroll
        for (int m = 0; m < LD; ++m) {
            const float e = enc[m];
            a1 = fmaf(e,        W1[m * HID + tid],        a1);
            a2 = fmaf(fabsf(e), W1[(LD + m) * HID + tid], a2);
        }
        sv1[tid] = a1;
        sv2[tid] = a2;
    }

    float S = 0.f;
    #pragma unroll
    for (int m = 0; m < LD; ++m) { const float e = enc[m]; S = fmaf(e, e, S); }
    const float inv  = 1.0f / (S + 1e-12f);
    const float selt = S * inv;

    bf16x8 a2f[4][2];
    #pragma unroll
    for (int mt = 0; mt < 4; ++mt)
        #pragma unroll
        for (int kt = 0; kt < 2; ++kt) {
            u32x4 uu;
            #pragma unroll
            for (int p = 0; p < 4; ++p) {
                const int k0 = 32*kt + 8*g + 2*p;
                uu[p] = cvt_pk_bf16(W2[k0 * HID + 16*mt + c],
                                    W2[(k0 + 1) * HID + 16*mt + c]);
            }
            a2f[mt][kt] = __builtin_bit_cast(bf16x8, uu);
        }
    bf16x8 a3f[2][2];
    #pragma unroll
    for (int mt = 0; mt < 2; ++mt)
        #pragma unroll
        for (int kt = 0; kt < 2; ++kt) {
            u32x4 uu;
            #pragma unroll
            for (int p = 0; p < 4; ++p) {
                const int k0 = 32*kt + 8*g + 2*p;
                uu[p] = cvt_pk_bf16(W3[k0 * LD + 16*mt + c],
                                    W3[(k0 + 1) * LD + 16*mt + c]);
            }
            a3f[mt][kt] = __builtin_bit_cast(bf16x8, uu);
        }

    f32x4 b2q[4], b3q[2];
    #pragma unroll
    for (int mt = 0; mt < 4; ++mt)
        b2q[mt] = *reinterpret_cast<const f32x4*>(b2 + 16*mt + 4*g);
    #pragma unroll
    for (int mt = 0; mt < 2; ++mt)
        b3q[mt] = *reinterpret_cast<const f32x4*>(b3 + 16*mt + 4*g);

    const v2f* encv = (const v2f*)enc;
    v2f encp[2][2];
    #pragma unroll
    for (int mt = 0; mt < 2; ++mt) {
        encp[mt][0] = encv[8*mt + 2*g + 0] * (0.25f * inv);
        encp[mt][1] = encv[8*mt + 2*g + 1] * (0.25f * inv);
    }

    __syncthreads();

    const v2f* sv1v = (const v2f*)sv1;
    const v2f* sv2v = (const v2f*)sv2;
    const v2f* b1v  = (const v2f*)b1;
    v2f v1p[2][4], v2p[2][4], b1p[2][4];
    #pragma unroll
    for (int kt = 0; kt < 2; ++kt)
        #pragma unroll
        for (int p = 0; p < 4; ++p) {
            const int idx = 16*kt + 4*g + p;
            v1p[kt][p] = sv1v[idx];
            v2p[kt][p] = sv2v[idx];
            b1p[kt][p] = b1v[idx];
        }

    short* const xs0 = &xT[w][0][0][0];
    short* const xs1 = &xT[w][1][0][0];
    const int swz    = (c & 7) << 1;
    const int rowoff = c * 64;

    auto stageA = [&](float a_, float d_, short* xsl) {
        const v2f av = { a_, a_ };
        const v2f dv = { d_, d_ };
        f32x4 acc[4];
        #pragma unroll
        for (int kt = 0; kt < 2; ++kt) {
            u32x4 uu;
            #pragma unroll
            for (int p = 0; p < 4; ++p) {
                const v2f pre = av * v1p[kt][p] + (dv * v2p[kt][p] + b1p[kt][p]);
                const v2f gg  = gelu2(pre);
                uu[p] = cvt_pk_bf16(gg.x, gg.y);
            }
            const bf16x8 bfrag = __builtin_bit_cast(bf16x8, uu);
            #pragma unroll
            for (int mt = 0; mt < 4; ++mt)
                acc[mt] = __builtin_amdgcn_mfma_f32_16x16x32_bf16(
                              a2f[mt][kt], bfrag, kt == 0 ? b2q[mt] : acc[mt],
                              0, 0, 0);
        }
        #pragma unroll
        for (int mt = 0; mt < 4; ++mt) {
            const v2f y01 = gelu2((v2f){acc[mt][0], acc[mt][1]});
            const v2f y23 = gelu2((v2f){acc[mt][2], acc[mt][3]});
            uint2 pk;
            pk.x = cvt_pk_bf16(y01.x, y01.y);
            pk.y = cvt_pk_bf16(y23.x, y23.y);
            const int cs = (4*mt + g) ^ swz;
            *reinterpret_cast<uint2*>(xsl + rowoff + cs*4) = pk;
        }
    };
    auto stageB = [&](const short* xsl) -> float {
        f32x4 a3acc[2];
        #pragma unroll
        for (int kt = 0; kt < 2; ++kt) {
            const int p = (8*kt + 2*g) ^ swz;
            const bf16x8 bfr =
                *reinterpret_cast<const bf16x8*>(xsl + rowoff + p*4);
            #pragma unroll
            for (int mt = 0; mt < 2; ++mt)
                a3acc[mt] = __builtin_amdgcn_mfma_f32_16x16x32_bf16(
                                a3f[mt][kt], bfr, kt == 0 ? b3q[mt] : a3acc[mt],
                                0, 0, 0);
        }
        v2f sacc = {0.f, 0.f};
        #pragma unroll
        for (int mt = 0; mt < 2; ++mt) {
            sacc += tanh2((v2f){a3acc[mt][0], a3acc[mt][1]}) * encp[mt][0];
            sacc += tanh2((v2f){a3acc[mt][2], a3acc[mt][3]}) * encp[mt][1];
        }
        float s_ = sacc.x + sacc.y;
        s_ += __shfl_xor(s_, 16);
        s_ += __shfl_xor(s_, 32);
        return s_;
    };

    for (int sid = blockIdx.x * WPB + w; sid < TOTAL_SPANS; sid += GRID * WPB) {
        const int row  = sid / SPANS;
        const int span = sid - row * SPANS;
        const int n0   = span * 63;
        const float* __restrict__ urow = u + row * NN;

        float af[4], df[4];
        if (n0 >= 1 && n0 + 63 <= NN - 1) {
            #pragma unroll
            for (int nt = 0; nt < 4; ++nt) {
                const int i = n0 + 16*nt + c;
                const float ul = urow[i - 1], ur = urow[i];
                af[nt] = ul + ur;
                df[nt] = fabsf(ur - ul);
            }
        } else {
            #pragma unroll
            for (int nt = 0; nt < 4; ++nt) {
                const int i = n0 + 16*nt + c;
                int il = i - 1; il = il < 0 ? 0 : (il > NN-1 ? NN-1 : il);
                const int ir = i > NN-1 ? NN-1 : i;
                const float ul = urow[il], ur = urow[ir];
                af[nt] = ul + ur;
                df[nt] = fabsf(ur - ul);
            }
        }

        float phi0, phi1, phi2, phi3;
        stageA(af[0], df[0], xs0);
        stageA(af[1], df[1], xs1);
        phi0 = stageB(xs0);
        stageA(af[2], df[2], xs0);
        phi1 = stageB(xs1);
        stageA(af[3], df[3], xs1);
        phi2 = stageB(xs0);
        phi3 = stageB(xs1);

        float myphi = phi0;
        if (g == 1) myphi = phi1;
        if (g == 2) myphi = phi2;
        if (g == 3) myphi = phi3;
        const float pn1 = __shfl_down(myphi, 1);

        if (l < 63) {
            const int n = n0 + l;
            if (n < NN) {
                out[row * NN + n] = fmaf(urow[n], selt, -0.5f * (pn1 - myphi));
            }
        }
    }
}

// =====================  launcher  =====================
extern "C" void kernel_launch(void* const* d_in, const int* in_sizes, int n_in,
                              void* d_out, int out_size, void* d_ws, size_t ws_size,
                              hipStream_t stream) {
    const float* u   = (const float*)d_in[0];
    const float* enc = (const float*)d_in[1];
    const float* W1  = (const float*)d_in[2];
    const float* b1  = (const float*)d_in[3];
    const float* W2  = (const float*)d_in[4];
    const float* b2  = (const float*)d_in[5];
    const float* W3  = (const float*)d_in[6];
    const float* b3  = (const float*)d_in[7];
    float* out = (float*)d_out;

    if (ws_size >= (size_t)TBL_BYTES) {
        float* tg = (float*)d_ws;
        build_table_mfma4<<<BGRID, 256, 0, stream>>>(enc, W1, b1, W2, b2, W3, b3, tg);
        apply_table<<<AGRID, APB, 0, stream>>>(u, tg, out);
    } else {
        fluxgnn_mfma<<<GRID, 64 * WPB, 0, stream>>>(u, enc, W1, b1, W2, b2, W3, b3, out);
    }
}

// Round 16
// 15.642 us; speedup vs baseline: 1.0566x; 1.0566x over previous
//
#include <hip/hip_runtime.h>
#include <math.h>
#include <stdint.h>

// FluxGNN1DLatent — round 16: exact revert to round-14 (best measured,
// 15.67 us). r15's apply-side changes (1 span/wave + shfl_up halo) both
// regressed: doubled table-preload traffic and a DS-pipe dependency before
// the first lookup. This configuration is fixed-cost-dominated:
// ~2.7 us mandatory HBM (16.8 MB) + build prologue + 2 launches.
// Structure: phi[i] = F(a_i, d_i), a = u_l+u_r in [0,2), d = |u_r-u_l| in
// [0,1); T = 0.5*phi tabulated on a 65x63 grid (built by the r7 MFMA wave
// engine, 32 blocks x 4 waves); apply does 2 interfaces/lane, 4 LDS gathers
// + 3 lerps each, out = u*selt - (T(n+1)-T(n)).
// Fallback: full round-7 kernel if ws_size < table.

#define LD    32
#define HID   64
#define NN    65536
#define BB    32
#define SPANS 1041                 // fallback kernel: ceil(65536/63)
#define TOTAL_SPANS (BB * SPANS)   // 33312

// ---- table geometry ----
#define NA    65                   // a = ia/32,  ia in [0,64]
#define ND    63                   // d = id/62,  id in [0,62]
#define NPTS  (NA * ND)            // 4095
#define TBL_BYTES ((NPTS + 1) * 4) // +1 slot for selt = 16384 B
#define WPB   4
#define BGRID 32                   // 32 blocks x 4 waves x 32 pts = 4096 slots

typedef __attribute__((ext_vector_type(8))) short bf16x8;
typedef __attribute__((ext_vector_type(4))) float f32x4;
typedef __attribute__((ext_vector_type(2))) float v2f;
typedef __attribute__((ext_vector_type(4))) unsigned int u32x4;

__device__ __forceinline__ uint32_t cvt_pk_bf16(float lo, float hi) {
    uint32_t r;
    asm("v_cvt_pk_bf16_f32 %0, %1, %2" : "=v"(r) : "v"(lo), "v"(hi));
    return r;
}
// gelu(x) = x*(1 - 1/(exp2(C1*x + C3*x^3)+1)); C1=2*log2e*0.79788456
__device__ __forceinline__ v2f gelu2(v2f x) {
    const v2f xx    = x * x;
    const v2f inner = xx * 0.10294322f + 2.3022077f;
    const v2f arg   = x * inner;
    v2f t;
    t.x = __builtin_amdgcn_exp2f(arg.x);
    t.y = __builtin_amdgcn_exp2f(arg.y);
    const v2f dd = t + 1.0f;
    v2f r;
    r.x = __builtin_amdgcn_rcpf(dd.x);
    r.y = __builtin_amdgcn_rcpf(dd.y);
    return x - x * r;
}
// tanh(y) = 1 - 2/(exp2(2*log2e*y)+1)
__device__ __forceinline__ v2f tanh2(v2f y) {
    const v2f a = y * 2.8853901f;
    v2f t;
    t.x = __builtin_amdgcn_exp2f(a.x);
    t.y = __builtin_amdgcn_exp2f(a.y);
    const v2f dd = t + 1.0f;
    v2f r;
    r.x = __builtin_amdgcn_rcpf(dd.x);
    r.y = __builtin_amdgcn_rcpf(dd.y);
    return 1.0f - 2.0f * r;
}

// ============  kernel 1: build table (r7 engine, 32 pts/wave)  ============
__global__ __launch_bounds__(256, 2)
void build_table_mfma4(const float* __restrict__ enc,
                       const float* __restrict__ W1, const float* __restrict__ b1,
                       const float* __restrict__ W2, const float* __restrict__ b2,
                       const float* __restrict__ W3, const float* __restrict__ b3,
                       float* __restrict__ tg)
{
    __shared__ __align__(16) short xT[WPB][2][16][64];
    __shared__ __align__(16) float sv1[HID];
    __shared__ __align__(16) float sv2[HID];

    const int tid = threadIdx.x;
    const int w   = tid >> 6;
    const int l   = tid & 63;
    const int c   = l & 15;
    const int g   = l >> 4;

    if (tid < HID) {
        float a1 = 0.f, a2 = 0.f;
        #pragma unroll
        for (int m = 0; m < LD; ++m) {
            const float e = enc[m];
            a1 = fmaf(e,        W1[m * HID + tid],        a1);
            a2 = fmaf(fabsf(e), W1[(LD + m) * HID + tid], a2);
        }
        sv1[tid] = a1;
        sv2[tid] = a2;
    }

    float S = 0.f;
    #pragma unroll
    for (int m = 0; m < LD; ++m) { const float e = enc[m]; S = fmaf(e, e, S); }
    const float inv = 1.0f / (S + 1e-12f);

    bf16x8 a2f[4][2];
    #pragma unroll
    for (int mt = 0; mt < 4; ++mt)
        #pragma unroll
        for (int kt = 0; kt < 2; ++kt) {
            u32x4 uu;
            #pragma unroll
            for (int p = 0; p < 4; ++p) {
                const int k0 = 32*kt + 8*g + 2*p;
                uu[p] = cvt_pk_bf16(W2[k0 * HID + 16*mt + c],
                                    W2[(k0 + 1) * HID + 16*mt + c]);
            }
            a2f[mt][kt] = __builtin_bit_cast(bf16x8, uu);
        }
    bf16x8 a3f[2][2];
    #pragma unroll
    for (int mt = 0; mt < 2; ++mt)
        #pragma unroll
        for (int kt = 0; kt < 2; ++kt) {
            u32x4 uu;
            #pragma unroll
            for (int p = 0; p < 4; ++p) {
                const int k0 = 32*kt + 8*g + 2*p;
                uu[p] = cvt_pk_bf16(W3[k0 * LD + 16*mt + c],
                                    W3[(k0 + 1) * LD + 16*mt + c]);
            }
            a3f[mt][kt] = __builtin_bit_cast(bf16x8, uu);
        }

    f32x4 b2q[4], b3q[2];
    #pragma unroll
    for (int mt = 0; mt < 4; ++mt)
        b2q[mt] = *reinterpret_cast<const f32x4*>(b2 + 16*mt + 4*g);
    #pragma unroll
    for (int mt = 0; mt < 2; ++mt)
        b3q[mt] = *reinterpret_cast<const f32x4*>(b3 + 16*mt + 4*g);

    // enc pairs scaled by 0.125*inv: tg holds T = 0.5*phi
    const v2f* encv = (const v2f*)enc;
    v2f encp[2][2];
    #pragma unroll
    for (int mt = 0; mt < 2; ++mt) {
        encp[mt][0] = encv[8*mt + 2*g + 0] * (0.125f * inv);
        encp[mt][1] = encv[8*mt + 2*g + 1] * (0.125f * inv);
    }

    __syncthreads();

    const v2f* sv1v = (const v2f*)sv1;
    const v2f* sv2v = (const v2f*)sv2;
    const v2f* b1v  = (const v2f*)b1;
    v2f v1p[2][4], v2p[2][4], b1p[2][4];
    #pragma unroll
    for (int kt = 0; kt < 2; ++kt)
        #pragma unroll
        for (int p = 0; p < 4; ++p) {
            const int idx = 16*kt + 4*g + p;
            v1p[kt][p] = sv1v[idx];
            v2p[kt][p] = sv2v[idx];
            b1p[kt][p] = b1v[idx];
        }

    short* const xs0 = &xT[w][0][0][0];
    short* const xs1 = &xT[w][1][0][0];
    const int swz    = (c & 7) << 1;
    const int rowoff = c * 64;

    auto stageA = [&](float a_, float d_, short* xsl) {
        const v2f av = { a_, a_ };
        const v2f dv = { d_, d_ };
        f32x4 acc[4];
        #pragma unroll
        for (int kt = 0; kt < 2; ++kt) {
            u32x4 uu;
            #pragma unroll
            for (int p = 0; p < 4; ++p) {
                const v2f pre = av * v1p[kt][p] + (dv * v2p[kt][p] + b1p[kt][p]);
                const v2f gg  = gelu2(pre);
                uu[p] = cvt_pk_bf16(gg.x, gg.y);
            }
            const bf16x8 bfrag = __builtin_bit_cast(bf16x8, uu);
            #pragma unroll
            for (int mt = 0; mt < 4; ++mt)
                acc[mt] = __builtin_amdgcn_mfma_f32_16x16x32_bf16(
                              a2f[mt][kt], bfrag, kt == 0 ? b2q[mt] : acc[mt],
                              0, 0, 0);
        }
        #pragma unroll
        for (int mt = 0; mt < 4; ++mt) {
            const v2f y01 = gelu2((v2f){acc[mt][0], acc[mt][1]});
            const v2f y23 = gelu2((v2f){acc[mt][2], acc[mt][3]});
            uint2 pk;
            pk.x = cvt_pk_bf16(y01.x, y01.y);
            pk.y = cvt_pk_bf16(y23.x, y23.y);
            const int cs = (4*mt + g) ^ swz;
            *reinterpret_cast<uint2*>(xsl + rowoff + cs*4) = pk;
        }
    };
    auto stageB = [&](const short* xsl) -> float {
        f32x4 a3acc[2];
        #pragma unroll
        for (int kt = 0; kt < 2; ++kt) {
            const int p = (8*kt + 2*g) ^ swz;
            const bf16x8 bfr =
                *reinterpret_cast<const bf16x8*>(xsl + rowoff + p*4);
            #pragma unroll
            for (int mt = 0; mt < 2; ++mt)
                a3acc[mt] = __builtin_amdgcn_mfma_f32_16x16x32_bf16(
                                a3f[mt][kt], bfr, kt == 0 ? b3q[mt] : a3acc[mt],
                                0, 0, 0);
        }
        v2f sacc = {0.f, 0.f};
        #pragma unroll
        for (int mt = 0; mt < 2; ++mt) {
            sacc += tanh2((v2f){a3acc[mt][0], a3acc[mt][1]}) * encp[mt][0];
            sacc += tanh2((v2f){a3acc[mt][2], a3acc[mt][3]}) * encp[mt][1];
        }
        float s_ = sacc.x + sacc.y;
        s_ += __shfl_xor(s_, 16);
        s_ += __shfl_xor(s_, 32);
        return s_;
    };

    // ---- this wave's 32 table points (clamped to the table domain)
    const int wbase = (blockIdx.x * WPB + w) * 32;
    float af[2], df[2];
    #pragma unroll
    for (int nt = 0; nt < 2; ++nt) {
        int pp = wbase + 16*nt + c;
        pp = pp < NPTS ? pp : NPTS - 1;        // clamp OOB tail lanes
        const int ia  = pp / ND;
        const int idd = pp - ia * ND;
        af[nt] = (float)ia  * (1.0f / 32.0f);
        df[nt] = (float)idd * (1.0f / 62.0f);
    }

    // pipelined: B0 reads xs0 a full stage after A0's store (r7 discipline)
    float phi0, phi1;
    stageA(af[0], df[0], xs0);
    stageA(af[1], df[1], xs1);
    phi0 = stageB(xs0);
    phi1 = stageB(xs1);

    const float myphi = (g & 1) ? phi1 : phi0;   // l<32: g in {0,1}
    const int pid = wbase + l;
    if (l < 32 && pid < NPTS) tg[pid] = myphi;
    if (blockIdx.x == 0 && tid == 0) tg[NPTS] = S * inv;   // selt slot
}

// =====================  kernel 2: apply table (2 interfaces/lane)  ==========
#define APB   1024
#define AGRID 512
#define AWAVES (AGRID * (APB / 64))   // 8192
#define SPANS_A 517                   // ceil(65536/127)
#define TOTAL_SPANS_A (BB * SPANS_A)  // 16544

__global__ __launch_bounds__(APB)
void apply_table(const float* __restrict__ u,
                 const float* __restrict__ tg,
                 float* __restrict__ out)
{
    __shared__ __align__(16) float T[NPTS];       // 16380 B

    const int tid = threadIdx.x;
    {   // vectorized preload: 1023 float4 + 3-element tail (4095 = 1023*4+3)
        const float4* tg4 = reinterpret_cast<const float4*>(tg);
        float4* T4 = reinterpret_cast<float4*>(T);
        for (int k4 = tid; k4 < NPTS / 4; k4 += APB) T4[k4] = tg4[k4];
        if (tid < (NPTS & 3)) T[(NPTS & ~3) + tid] = tg[(NPTS & ~3) + tid];
    }
    const float selt = tg[NPTS];
    __syncthreads();

    const int w = tid >> 6;
    const int l = tid & 63;

    auto lookup = [&](float a, float d) -> float {
        const float ta = a * 32.0f;
        const int   ia = (int)ta;
        const float fa = ta - (float)ia;
        const float td = d * 62.0f;
        const int   idn = (int)td;
        const float fd = td - (float)idn;
        const int base = ia * ND + idn;
        const float g00 = T[base];
        const float g01 = T[base + 1];
        const float g10 = T[base + ND];
        const float g11 = T[base + ND + 1];
        const float gA = fmaf(fd, g01 - g00, g00);
        const float gB = fmaf(fd, g11 - g10, g10);
        return fmaf(fa, gB - gA, gA);             // T = 0.5*phi
    };

    for (int sid = blockIdx.x * (APB / 64) + w; sid < TOTAL_SPANS_A; sid += AWAVES) {
        const int row  = sid / SPANS_A;
        const int span = sid - row * SPANS_A;
        const int n0   = span * 127;
        const float* __restrict__ urow = u + row * NN;

        const int i0 = n0 + 2 * l;                 // interfaces i0, i0+1
        int il = i0 - 1; il = il < 0 ? 0 : (il > NN - 1 ? NN - 1 : il);
        const int im = i0     > NN - 1 ? NN - 1 : i0;
        const int ir = i0 + 1 > NN - 1 ? NN - 1 : i0 + 1;
        const float um1 = urow[il];
        const float u0  = urow[im];
        const float u1  = urow[ir];

        const float F0 = lookup(um1 + u0, fabsf(u0 - um1));   // T(i0)
        const float F1 = lookup(u0 + u1, fabsf(u1 - u0));     // T(i0+1)
        const float pn2 = __shfl_down(F0, 1);                 // T(i0+2)

        const int n = n0 + 2 * l;
        if (2 * l < 127 && n < NN)
            out[row * NN + n] = fmaf(u0, selt, -(F1 - F0));
        if (2 * l + 1 < 127 && n + 1 < NN)
            out[row * NN + n + 1] = fmaf(u1, selt, -(pn2 - F1));
    }
}

// =====================  fallback: round-7 MFMA kernel  =====================
#define GRID  2048

__global__ __launch_bounds__(256, 2)
void fluxgnn_mfma(const float* __restrict__ u,  const float* __restrict__ enc,
                  const float* __restrict__ W1, const float* __restrict__ b1,
                  const float* __restrict__ W2, const float* __restrict__ b2,
                  const float* __restrict__ W3, const float* __restrict__ b3,
                  float* __restrict__ out)
{
    __shared__ __align__(16) short xT[WPB][2][16][64];
    __shared__ __align__(16) float sv1[HID];
    __shared__ __align__(16) float sv2[HID];

    const int tid = threadIdx.x;
    const int w   = tid >> 6;
    const int l   = tid & 63;
    const int c   = l & 15;
    const int g   = l >> 4;

    if (tid < HID) {
        float a1 = 0.f, a2 = 0.f;
        #pragma unroll
        for (int m = 0; m < LD; ++m) {
            const float e = enc[m];
            a1 = fmaf(e,        W1[m * HID + tid],        a1);
            a2 = fmaf(fabsf(e), W1[(LD + m) * HID + tid], a2);
        }
        sv1[tid] = a1;
        sv2[tid] = a2;
    }

    float S = 0.f;
    #pragma unroll
    for (int m = 0; m < LD; ++m) { const float e = enc[m]; S = fmaf(e, e, S); }
    const float inv  = 1.0f / (S + 1e-12f);
    const float selt = S * inv;

    bf16x8 a2f[4][2];
    #pragma unroll
    for (int mt = 0; mt < 4; ++mt)
        #pragma unroll
        for (int kt = 0; kt < 2; ++kt) {
            u32x4 uu;
            #pragma unroll
            for (int p = 0; p < 4; ++p) {
                const int k0 = 32*kt + 8*g + 2*p;
                uu[p] = cvt_pk_bf16(W2[k0 * HID + 16*mt + c],
                                    W2[(k0 + 1) * HID + 16*mt + c]);
            }
            a2f[mt][kt] = __builtin_bit_cast(bf16x8, uu);
        }
    bf16x8 a3f[2][2];
    #pragma unroll
    for (int mt = 0; mt < 2; ++mt)
        #pragma unroll
        for (int kt = 0; kt < 2; ++kt) {
            u32x4 uu;
            #pragma unroll
            for (int p = 0; p < 4; ++p) {
                const int k0 = 32*kt + 8*g + 2*p;
                uu[p] = cvt_pk_bf16(W3[k0 * LD + 16*mt + c],
                                    W3[(k0 + 1) * LD + 16*mt + c]);
            }
            a3f[mt][kt] = __builtin_bit_cast(bf16x8, uu);
        }

    f32x4 b2q[4], b3q[2];
    #pragma unroll
    for (int mt = 0; mt < 4; ++mt)
        b2q[mt] = *reinterpret_cast<const f32x4*>(b2 + 16*mt + 4*g);
    #pragma unroll
    for (int mt = 0; mt < 2; ++mt)
        b3q[mt] = *reinterpret_cast<const f32x4*>(b3 + 16*mt + 4*g);

    const v2f* encv = (const v2f*)enc;
    v2f encp[2][2];
    #pragma unroll
    for (int mt = 0; mt < 2; ++mt) {
        encp[mt][0] = encv[8*mt + 2*g + 0] * (0.25f * inv);
        encp[mt][1] = encv[8*mt + 2*g + 1] * (0.25f * inv);
    }

    __syncthreads();

    const v2f* sv1v = (const v2f*)sv1;
    const v2f* sv2v = (const v2f*)sv2;
    const v2f* b1v  = (const v2f*)b1;
    v2f v1p[2][4], v2p[2][4], b1p[2][4];
    #pragma unroll
    for (int kt = 0; kt < 2; ++kt)
        #pragma unroll
        for (int p = 0; p < 4; ++p) {
            const int idx = 16*kt + 4*g + p;
            v1p[kt][p] = sv1v[idx];
            v2p[kt][p] = sv2v[idx];
            b1p[kt][p] = b1v[idx];
        }

    short* const xs0 = &xT[w][0][0][0];
    short* const xs1 = &xT[w][1][0][0];
    const int swz    = (c & 7) << 1;
    const int rowoff = c * 64;

    auto stageA = [&](float a_, float d_, short* xsl) {
        const v2f av = { a_, a_ };
        const v2f dv = { d_, d_ };
        f32x4 acc[4];
        #pragma unroll
        for (int kt = 0; kt < 2; ++kt) {
            u32x4 uu;
            #pragma unroll
            for (int p = 0; p < 4; ++p) {
                const v2f pre = av * v1p[kt][p] + (dv * v2p[kt][p] + b1p[kt][p]);
                const v2f gg  = gelu2(pre);
                uu[p] = cvt_pk_bf16(gg.x, gg.y);
            }
            const bf16x8 bfrag = __builtin_bit_cast(bf16x8, uu);
            #pragma unroll
            for (int mt = 0; mt < 4; ++mt)
                acc[mt] = __builtin_amdgcn_mfma_f32_16x16x32_bf16(
                              a2f[mt][kt], bfrag, kt == 0 ? b2q[mt] : acc[mt],
                              0, 0, 0);
        }
        #pragma unroll
        for (int mt = 0; mt < 4; ++mt) {
            const v2f y01 = gelu2((v2f){acc[mt][0], acc[mt][1]});
            const v2f y23 = gelu2((v2f){acc[mt][2], acc[mt][3]});
            uint2 pk;
            pk.x = cvt_pk_bf16(y01.x, y01.y);
            pk.y = cvt_pk_bf16(y23.x, y23.y);
            const int cs = (4*mt + g) ^ swz;
            *reinterpret_cast<uint2*>(xsl + rowoff + cs*4) = pk;
        }
    };
    auto stageB = [&](const short* xsl) -> float {
        f32x4 a3acc[2];
        #pragma unroll
        for (int kt = 0; kt < 2; ++kt) {
            const int p = (8*kt + 2*g) ^ swz;
            const bf16x8 bfr =
                *reinterpret_cast<const bf16x8*>(xsl + rowoff + p*4);
            #pragma unroll
            for (int mt = 0; mt < 2; ++mt)
                a3acc[mt] = __builtin_amdgcn_mfma_f32_16x16x32_bf16(
                                a3f[mt][kt], bfr, kt == 0 ? b3q[mt] : a3acc[mt],
                                0, 0, 0);
        }
        v2f sacc = {0.f, 0.f};
        #pragma unroll
        for (int mt = 0; mt < 2; ++mt) {
            sacc += tanh2((v2f){a3acc[mt][0], a3acc[mt][1]}) * encp[mt][0];
            sacc += tanh2((v2f){a3acc[mt][2], a3acc[mt][3]}) * encp[mt][1];
        }
        float s_ = sacc.x + sacc.y;
        s_ += __shfl_xor(s_, 16);
        s_ += __shfl_xor(s_, 32);
        return s_;
    };

    for (int sid = blockIdx.x * WPB + w; sid < TOTAL_SPANS; sid += GRID * WPB) {
        const int row  = sid / SPANS;
        const int span = sid - row * SPANS;
        const int n0   = span * 63;
        const float* __restrict__ urow = u + row * NN;

        float af[4], df[4];
        if (n0 >= 1 && n0 + 63 <= NN - 1) {
            #pragma unroll
            for (int nt = 0; nt < 4; ++nt) {
                const int i = n0 + 16*nt + c;
                const float ul = urow[i - 1], ur = urow[i];
                af[nt] = ul + ur;
                df[nt] = fabsf(ur - ul);
            }
        } else {
            #pragma unroll
            for (int nt = 0; nt < 4; ++nt) {
                const int i = n0 + 16*nt + c;
                int il = i - 1; il = il < 0 ? 0 : (il > NN-1 ? NN-1 : il);
                const int ir = i > NN-1 ? NN-1 : i;
                const float ul = urow[il], ur = urow[ir];
                af[nt] = ul + ur;
                df[nt] = fabsf(ur - ul);
            }
        }

        float phi0, phi1, phi2, phi3;
        stageA(af[0], df[0], xs0);
        stageA(af[1], df[1], xs1);
        phi0 = stageB(xs0);
        stageA(af[2], df[2], xs0);
        phi1 = stageB(xs1);
        stageA(af[3], df[3], xs1);
        phi2 = stageB(xs0);
        phi3 = stageB(xs1);

        float myphi = phi0;
        if (g == 1) myphi = phi1;
        if (g == 2) myphi = phi2;
        if (g == 3) myphi = phi3;
        const float pn1 = __shfl_down(myphi, 1);

        if (l < 63) {
            const int n = n0 + l;
            if (n < NN) {
                out[row * NN + n] = fmaf(urow[n], selt, -0.5f * (pn1 - myphi));
            }
        }
    }
}

// =====================  launcher  =====================
extern "C" void kernel_launch(void* const* d_in, const int* in_sizes, int n_in,
                              void* d_out, int out_size, void* d_ws, size_t ws_size,
                              hipStream_t stream) {
    const float* u   = (const float*)d_in[0];
    const float* enc = (const float*)d_in[1];
    const float* W1  = (const float*)d_in[2];
    const float* b1  = (const float*)d_in[3];
    const float* W2  = (const float*)d_in[4];
    const float* b2  = (const float*)d_in[5];
    const float* W3  = (const float*)d_in[6];
    const float* b3  = (const float*)d_in[7];
    float* out = (float*)d_out;

    if (ws_size >= (size_t)TBL_BYTES) {
        float* tg = (float*)d_ws;
        build_table_mfma4<<<BGRID, 256, 0, stream>>>(enc, W1, b1, W2, b2, W3, b3, tg);
        apply_table<<<AGRID, APB, 0, stream>>>(u, tg, out);
    } else {
        fluxgnn_mfma<<<GRID, 64 * WPB, 0, stream>>>(u, enc, W1, b1, W2, b2, W3, b3, out);
    }
}